// Round 5
// baseline (332.036 us; speedup 1.0000x reference)
//
#include <hip/hip_runtime.h>
#include <math.h>

#define NUM_POINTS 64
#define OUT_DIMS 128
#define BLOCK_THREADS 512
#define ELEMS_PER_BLOCK 512
#define PAD_LO 4
#define PAD_HI 4
#define LDS_ROWS (NUM_POINTS + PAD_LO + PAD_HI)  // 72 rows

typedef _Float16 half4v __attribute__((ext_vector_type(4)));
typedef _Float16 half8v __attribute__((ext_vector_type(8)));
typedef float f32x4 __attribute__((ext_vector_type(4)));  // clang-native for
// __builtin_nontemporal_store (HIP's float4 class type is rejected).

// Weights: w_j = cos^2(pi*d_j/8), d_j = t - j, t = xs - p0 in [3,4).
// cos^2(pi*d/8) = 0.5 + 0.5*cos(pi*d/4); taps spaced pi/4 apart -> all 8
// weights from ONE sin + ONE cos. Interior: the 8 cos terms cancel exactly,
// wsum == 4, weights built at final scale (0.125 +- ...).
//
// fp16 embeddings in LDS (one ds_read_b128 = 8 dims per tap); fp32 accum.
// x-values software-pipelined one iteration ahead (kills the ~120cy LDS
// broadcast latency at the head of each iteration's dependency chain).
// Non-temporal stores: output is write-once, keep it out of L2's way.
__global__ __launch_bounds__(BLOCK_THREADS, 8) void ce_kernel(
    const float* __restrict__ x,
    const float* __restrict__ emb,
    float* __restrict__ out) {
  __shared__ _Float16 s_emb[LDS_ROWS * OUT_DIMS];  // 18432 B, rows -4..67
  __shared__ float s_x[ELEMS_PER_BLOCK];           // 2 KB

  const int tid = threadIdx.x;
  {
    const float4* e4 = (const float4*)emb;
    half4v* s4 = (half4v*)(s_emb + PAD_LO * OUT_DIMS);
#pragma unroll
    for (int i = 0; i < (NUM_POINTS * OUT_DIMS / 4) / BLOCK_THREADS; ++i) {
      const float4 v = e4[tid + i * BLOCK_THREADS];
      half4v h;
      h[0] = (_Float16)v.x; h[1] = (_Float16)v.y;
      h[2] = (_Float16)v.z; h[3] = (_Float16)v.w;
      s4[tid + i * BLOCK_THREADS] = h;
    }
    if (tid < (PAD_LO * OUT_DIMS / 2)) {  // zero pad rows -4..-1, 64..67
      ((unsigned*)s_emb)[tid] = 0u;
      ((unsigned*)(s_emb + (PAD_LO + NUM_POINTS) * OUT_DIMS))[tid] = 0u;
    }
    s_x[tid] = x[blockIdx.x * ELEMS_PER_BLOCK + tid];
  }
  __syncthreads();

  const int chunk = tid & 15;  // 16 chunks of 8 consecutive dims
  const int sub = tid >> 4;    // 32 elements per iteration per block
  const size_t base = (size_t)blockIdx.x * ELEMS_PER_BLOCK;
  const float RS2 = 0.70710678118654752f;  // sqrt(2)/2

  float xv = s_x[sub];  // iteration 0's x, prefetched

#pragma unroll 1
  for (int it = 0; it < ELEMS_PER_BLOCK / 32; ++it) {
    // prefetch next iteration's x early; latency hides under this iteration
    const float xv_next =
        (it < ELEMS_PER_BLOCK / 32 - 1) ? s_x[(it + 1) * 32 + sub] : 0.0f;

    const int e_local = it * 32 + sub;
    const float xs = (xv + 1.0f) * 32.0f;  // [-1,1] -> [0,64]
    const int p0 = (int)xs - 3;            // xs >= 0: trunc == floor
    const float t = xs - (float)p0;        // in [3,4)
    const float rev = t * 0.125f;          // pi*t/4 rad == t/8 revolutions
    const float c4 = 0.125f * __builtin_amdgcn_cosf(rev);
    const float s4 = 0.125f * __builtin_amdgcn_sinf(rev);
    const float u4 = RS2 * (c4 + s4);
    const float v4 = RS2 * (c4 - s4);

    float w[8];
    w[0] = 0.125f + c4;  w[1] = 0.125f + u4;
    w[2] = 0.125f + s4;  w[3] = 0.125f - v4;
    w[4] = 0.125f - c4;  w[5] = 0.125f - u4;
    w[6] = 0.125f - s4;  w[7] = 0.125f + v4;

    // Edge elements (~11%): renormalize over in-grid taps only.
    if (__builtin_expect((unsigned)p0 > 56u, 0)) {
      float ssum = 0.f;
#pragma unroll
      for (int j = 0; j < 8; ++j) {
        w[j] = ((unsigned)(p0 + j) < 64u) ? w[j] : 0.f;
        ssum += w[j];
      }
      const float inv = __builtin_amdgcn_rcpf(ssum);  // ssum >= ~0.24
#pragma unroll
      for (int j = 0; j < 8; ++j) w[j] *= inv;
    }

    // 8 taps x 1 ds_read_b128 (8 fp16 dims); fp32 accumulate.
    const _Float16* rowbase = s_emb + (p0 + PAD_LO) * OUT_DIMS + chunk * 8;
    float acc[8];
#pragma unroll
    for (int k = 0; k < 8; ++k) acc[k] = 0.0f;
#pragma unroll
    for (int j = 0; j < 8; ++j) {
      const half8v ev = *(const half8v*)(rowbase + j * OUT_DIMS);
      const float wj = w[j];
#pragma unroll
      for (int k = 0; k < 8; ++k)
        acc[k] = fmaf((float)ev[k], wj, acc[k]);
    }

    // per-lane 32B contiguous; quarter-wave covers 512B; nt = stream past L2
    float* op = out + (base + e_local) * (size_t)OUT_DIMS + chunk * 8;
    f32x4 lo = {acc[0], acc[1], acc[2], acc[3]};
    f32x4 hi = {acc[4], acc[5], acc[6], acc[7]};
    __builtin_nontemporal_store(lo, (f32x4*)op);
    __builtin_nontemporal_store(hi, (f32x4*)(op + 4));
    xv = xv_next;
  }
}

extern "C" void kernel_launch(void* const* d_in, const int* in_sizes, int n_in,
                              void* d_out, int out_size, void* d_ws, size_t ws_size,
                              hipStream_t stream) {
  const float* x = (const float*)d_in[0];    // (64, 8192) fp32
  const float* emb = (const float*)d_in[1];  // (64, 128) fp32
  float* out = (float*)d_out;                // (64, 8192, 128) fp32

  const int n = in_sizes[0];                 // 524288 elements
  const int blocks = n / ELEMS_PER_BLOCK;    // 1024 = exactly 4 per CU
  ce_kernel<<<blocks, BLOCK_THREADS, 0, stream>>>(x, emb, out);
}

// Round 6
// 264.265 us; speedup vs baseline: 1.2564x; 1.2564x over previous
//
#include <hip/hip_runtime.h>
#include <math.h>

#define NUM_POINTS 64
#define OUT_DIMS 128
#define BLOCK_THREADS 512
#define ELEMS_PER_BLOCK 512
#define PAD_LO 4
#define PAD_HI 4
#define LDS_ROWS (NUM_POINTS + PAD_LO + PAD_HI)  // 72 rows

typedef _Float16 half4v __attribute__((ext_vector_type(4)));
typedef _Float16 half8v __attribute__((ext_vector_type(8)));

// Weights: w_j = cos^2(pi*d_j/8), d_j = t - j, t = xs - p0 in [3,4).
// cos^2(pi*d/8) = 0.5 + 0.5*cos(pi*d/4); taps spaced pi/4 apart -> all 8
// weights from ONE sin + ONE cos. Interior: the 8 cos terms cancel exactly,
// wsum == 4, weights built at final scale (0.125 +- ...).
//
// fp16 embeddings in LDS (one ds_read_b128 = 8 dims per tap); fp32 accum.
// x-values software-pipelined one iteration ahead.
// Stores: PLAIN float4 through L2 — R5 measured nontemporal stores as a
// +72us regression (nt demotes the stream out of L2 write-coalescing);
// the normal path runs at 6.3+ TB/s. Do not reintroduce nt here.
__global__ __launch_bounds__(BLOCK_THREADS, 8) void ce_kernel(
    const float* __restrict__ x,
    const float* __restrict__ emb,
    float* __restrict__ out) {
  __shared__ _Float16 s_emb[LDS_ROWS * OUT_DIMS];  // 18432 B, rows -4..67
  __shared__ float s_x[ELEMS_PER_BLOCK];           // 2 KB

  const int tid = threadIdx.x;
  {
    const float4* e4 = (const float4*)emb;
    half4v* s4 = (half4v*)(s_emb + PAD_LO * OUT_DIMS);
#pragma unroll
    for (int i = 0; i < (NUM_POINTS * OUT_DIMS / 4) / BLOCK_THREADS; ++i) {
      const float4 v = e4[tid + i * BLOCK_THREADS];
      half4v h;
      h[0] = (_Float16)v.x; h[1] = (_Float16)v.y;
      h[2] = (_Float16)v.z; h[3] = (_Float16)v.w;
      s4[tid + i * BLOCK_THREADS] = h;
    }
    if (tid < (PAD_LO * OUT_DIMS / 2)) {  // zero pad rows -4..-1, 64..67
      ((unsigned*)s_emb)[tid] = 0u;
      ((unsigned*)(s_emb + (PAD_LO + NUM_POINTS) * OUT_DIMS))[tid] = 0u;
    }
    s_x[tid] = x[blockIdx.x * ELEMS_PER_BLOCK + tid];
  }
  __syncthreads();

  const int chunk = tid & 15;  // 16 chunks of 8 consecutive dims
  const int sub = tid >> 4;    // 32 elements per iteration per block
  const size_t base = (size_t)blockIdx.x * ELEMS_PER_BLOCK;
  const float RS2 = 0.70710678118654752f;  // sqrt(2)/2

  float xv = s_x[sub];  // iteration 0's x, prefetched

#pragma unroll 1
  for (int it = 0; it < ELEMS_PER_BLOCK / 32; ++it) {
    // prefetch next iteration's x; latency hides under this iteration
    const float xv_next =
        (it < ELEMS_PER_BLOCK / 32 - 1) ? s_x[(it + 1) * 32 + sub] : 0.0f;

    const int e_local = it * 32 + sub;
    const float xs = (xv + 1.0f) * 32.0f;  // [-1,1] -> [0,64]
    const int p0 = (int)xs - 3;            // xs >= 0: trunc == floor
    const float t = xs - (float)p0;        // in [3,4)
    const float rev = t * 0.125f;          // pi*t/4 rad == t/8 revolutions
    const float c4 = 0.125f * __builtin_amdgcn_cosf(rev);
    const float s4 = 0.125f * __builtin_amdgcn_sinf(rev);
    const float u4 = RS2 * (c4 + s4);
    const float v4 = RS2 * (c4 - s4);

    float w[8];
    w[0] = 0.125f + c4;  w[1] = 0.125f + u4;
    w[2] = 0.125f + s4;  w[3] = 0.125f - v4;
    w[4] = 0.125f - c4;  w[5] = 0.125f - u4;
    w[6] = 0.125f - s4;  w[7] = 0.125f + v4;

    // Edge elements (~11%): renormalize over in-grid taps only.
    if (__builtin_expect((unsigned)p0 > 56u, 0)) {
      float ssum = 0.f;
#pragma unroll
      for (int j = 0; j < 8; ++j) {
        w[j] = ((unsigned)(p0 + j) < 64u) ? w[j] : 0.f;
        ssum += w[j];
      }
      const float inv = __builtin_amdgcn_rcpf(ssum);  // ssum >= ~0.24
#pragma unroll
      for (int j = 0; j < 8; ++j) w[j] *= inv;
    }

    // 8 taps x 1 ds_read_b128 (8 fp16 dims); fp32 accumulate.
    const _Float16* rowbase = s_emb + (p0 + PAD_LO) * OUT_DIMS + chunk * 8;
    float acc[8];
#pragma unroll
    for (int k = 0; k < 8; ++k) acc[k] = 0.0f;
#pragma unroll
    for (int j = 0; j < 8; ++j) {
      const half8v ev = *(const half8v*)(rowbase + j * OUT_DIMS);
      const float wj = w[j];
#pragma unroll
      for (int k = 0; k < 8; ++k)
        acc[k] = fmaf((float)ev[k], wj, acc[k]);
    }

    // per-lane 32B contiguous; quarter-wave covers 512B per store pair
    float* op = out + (base + e_local) * (size_t)OUT_DIMS + chunk * 8;
    *(float4*)op = make_float4(acc[0], acc[1], acc[2], acc[3]);
    *(float4*)(op + 4) = make_float4(acc[4], acc[5], acc[6], acc[7]);
    xv = xv_next;
  }
}

extern "C" void kernel_launch(void* const* d_in, const int* in_sizes, int n_in,
                              void* d_out, int out_size, void* d_ws, size_t ws_size,
                              hipStream_t stream) {
  const float* x = (const float*)d_in[0];    // (64, 8192) fp32
  const float* emb = (const float*)d_in[1];  // (64, 128) fp32
  float* out = (float*)d_out;                // (64, 8192, 128) fp32

  const int n = in_sizes[0];                 // 524288 elements
  const int blocks = n / ELEMS_PER_BLOCK;    // 1024 = exactly 4 per CU
  ce_kernel<<<blocks, BLOCK_THREADS, 0, stream>>>(x, emb, out);
}